// Round 2
// baseline (371.929 us; speedup 1.0000x reference)
//
#include <hip/hip_runtime.h>

#define BB 256
#define CC 68
#define HH 64
#define WW 64
#define WAVES_PER_BLOCK 4   // 256 threads = 4 waves, each wave owns one heatmap

__global__ __launch_bounds__(256) void face_landmark_kernel(
    const float* __restrict__ pred_hm,   // [B,C,H,W]
    const float* __restrict__ center,    // [B,2]
    const float* __restrict__ scale,     // [B]
    float* __restrict__ out)             // [B,C,2]
{
    const int wave = threadIdx.x >> 6;
    const int lane = threadIdx.x & 63;
    const int bc   = blockIdx.x * WAVES_PER_BLOCK + wave;  // 0 .. B*C-1 (grid exact)
    const int b    = bc / CC;

    const float*  hm  = pred_hm + (size_t)bc * (HH * WW);
    const float4* hm4 = (const float4*)hm;

    // One wave scans the whole 64x64 heatmap: 16 float4 per lane (coalesced,
    // 16 KB/wave in flight). FOUR independent compare chains (one per float4
    // component) give 4x ILP vs a single serial chain; fi ascends per-thread,
    // so strict > keeps the first occurrence within each chain.
    float bv0 = -__builtin_inff(), bv1 = -__builtin_inff();
    float bv2 = -__builtin_inff(), bv3 = -__builtin_inff();
    int bi0 = 0, bi1 = 0, bi2 = 0, bi3 = 0;
#pragma unroll
    for (int k = 0; k < 16; ++k) {
        const int fi = lane + 64 * k;        // float4 index
        const float4 v = hm4[fi];
        if (v.x > bv0) { bv0 = v.x; bi0 = fi; }
        if (v.y > bv1) { bv1 = v.y; bi1 = fi; }
        if (v.z > bv2) { bv2 = v.z; bi2 = fi; }
        if (v.w > bv3) { bv3 = v.w; bi3 = fi; }
    }

    // Combine the 4 chains: max value, tie -> smallest flat index.
    // Flat indices are distinct across chains (component offset), so the
    // generic (>, ==&&<) compare yields the thread-global first occurrence.
    float best_v = bv0; int best_i = bi0 * 4 + 0;
    {
        const int f1 = bi1 * 4 + 1;
        if (bv1 > best_v || (bv1 == best_v && f1 < best_i)) { best_v = bv1; best_i = f1; }
        const int f2 = bi2 * 4 + 2;
        if (bv2 > best_v || (bv2 == best_v && f2 < best_i)) { best_v = bv2; best_i = f2; }
        const int f3 = bi3 * 4 + 3;
        if (bv3 > best_v || (bv3 == best_v && f3 < best_i)) { best_v = bv3; best_i = f3; }
    }

    // Wave-64 butterfly reduce; tie -> smaller flat index (first occurrence).
#pragma unroll
    for (int off = 32; off > 0; off >>= 1) {
        const float ov = __shfl_down(best_v, off, 64);
        const int   oi = __shfl_down(best_i, off, 64);
        if (ov > best_v || (ov == best_v && oi < best_i)) { best_v = ov; best_i = oi; }
    }

    // No __syncthreads, no LDS: each wave finishes its own heatmap.
    if (lane == 0) {
        const int idx = best_i;              // 0-based flat argmax
        const int iX = idx & (WW - 1);       // column
        const int iY = idx >> 6;             // row
        float px = (float)(iX + 1);          // 1-based
        float py = (float)(iY + 1);

        const bool interior = (iX > 0) && (iX < WW - 1) && (iY > 0) && (iY < HH - 1);
        if (interior) {
            // clip is a no-op when interior; loads hit L1/L2 (just streamed)
            const float dx = hm[iY * WW + iX + 1] - hm[iY * WW + iX - 1];
            const float dy = hm[(iY + 1) * WW + iX] - hm[(iY - 1) * WW + iX];
            px += (dx > 0.0f) ? 0.25f : ((dx < 0.0f) ? -0.25f : 0.0f);
            py += (dy > 0.0f) ? 0.25f : ((dy < 0.0f) ? -0.25f : 0.0f);
        }
        px -= 0.5f;
        py -= 0.5f;

        const float h  = 200.0f * scale[b];
        const float hr = h * (1.0f / (float)HH);     // h / res, res = H = 64
        const float ox = px * hr + center[b * 2 + 0] - 0.5f * h;
        const float oy = py * hr + center[b * 2 + 1] - 0.5f * h;

        ((float2*)out)[bc] = make_float2(ox, oy);
    }
}

extern "C" void kernel_launch(void* const* d_in, const int* in_sizes, int n_in,
                              void* d_out, int out_size, void* d_ws, size_t ws_size,
                              hipStream_t stream) {
    const float* pred_hm = (const float*)d_in[0];   // [256,68,64,64] f32
    const float* center  = (const float*)d_in[1];   // [256,2] f32
    const float* scale   = (const float*)d_in[2];   // [256] f32
    float* out = (float*)d_out;                     // [256,68,2] f32

    face_landmark_kernel<<<dim3((BB * CC) / WAVES_PER_BLOCK), dim3(256), 0, stream>>>(
        pred_hm, center, scale, out);
}